// Round 2
// baseline (14365.459 us; speedup 1.0000x reference)
//
#include <hip/hip_runtime.h>
#include <hip/hip_bf16.h>

// Problem constants
#define B_   128
#define T_   30
#define V_   10000
#define E_   512
#define H_   512
#define F_   4096
#define L_   2
#define VPAD 10112   // 79 * 128

typedef __attribute__((ext_vector_type(4))) float f32x4;
typedef __attribute__((ext_vector_type(8))) __bf16 bf16x8;
typedef __attribute__((ext_vector_type(8))) unsigned short u16x8;

__device__ __forceinline__ unsigned short f2bf(float x){
    unsigned int u = __float_as_uint(x);
    unsigned int r = (u + 0x7FFFu + ((u >> 16) & 1u)) >> 16;
    return (unsigned short)r;
}

// ---------------------------------------------------------------------------
// W_out [512][10000] f32  ->  WbT [VPAD][512] bf16 (transposed, zero-padded)
// ---------------------------------------------------------------------------
__global__ void __launch_bounds__(256) k_castWT(const float* __restrict__ W,
                                                unsigned short* __restrict__ WbT){
    __shared__ float tile[64][65];
    const int n0 = blockIdx.x * 64;
    const int k0 = blockIdx.y * 64;
    const int tid = threadIdx.x;
    for (int q = 0; q < 16; ++q){
        int idx = tid + q * 256;
        int kk = idx >> 6, nn = idx & 63;
        int n = n0 + nn;
        tile[kk][nn] = (n < V_) ? W[(size_t)(k0 + kk) * V_ + n] : 0.f;
    }
    __syncthreads();
    for (int q = 0; q < 16; ++q){
        int idx = tid + q * 256;
        int nn = idx >> 6, kk = idx & 63;
        WbT[(size_t)(n0 + nn) * 512 + k0 + kk] = f2bf(tile[kk][nn]);
    }
}

// ---------------------------------------------------------------------------
// x-part weights: W{u,r,c}[0][0:512][:] -> WxT section [512][512] bf16 transposed
// ---------------------------------------------------------------------------
__global__ void __launch_bounds__(256) k_castWxT(const float* __restrict__ src,
                                                 unsigned short* __restrict__ dst){
    __shared__ float tile[64][65];
    const int n0 = blockIdx.x * 64;   // 8
    const int k0 = blockIdx.y * 64;   // 8
    const int tid = threadIdx.x;
    for (int q = 0; q < 16; ++q){
        int idx = tid + q * 256;
        int kk = idx >> 6, nn = idx & 63;
        tile[kk][nn] = src[(size_t)(k0 + kk) * 512 + n0 + nn];
    }
    __syncthreads();
    for (int q = 0; q < 16; ++q){
        int idx = tid + q * 256;
        int nn = idx >> 6, kk = idx & 63;
        dst[(size_t)(n0 + nn) * 512 + k0 + kk] = f2bf(tile[kk][nn]);
    }
}

// ---------------------------------------------------------------------------
// Pack recurrence weights f32 -> lane-major tiles: dst[(g*Kq+kq)*256 + l*4 + ki]
//   = src[(koff + kq*4+ki)*512 + (g*64+l mod 512 via srcA/srcB split)]
// ---------------------------------------------------------------------------
__global__ void __launch_bounds__(256) k_prepW(float* __restrict__ dst,
                                               const float* __restrict__ srcA,
                                               const float* __restrict__ srcB,
                                               int koff, int Kq){
    const int idx = blockIdx.x * 256 + threadIdx.x;
    const int l = idx & 63;
    const int gk = idx >> 6;
    const int kq = gk % Kq;
    const int g  = gk / Kq;
    const int n = g * 64 + l;
    const float* s = (n < 512) ? srcA : srcB;
    const int nc = n & 511;
    const int k = koff + kq * 4;
    float4 v;
    v.x = s[(size_t)(k    ) * 512 + nc];
    v.y = s[(size_t)(k + 1) * 512 + nc];
    v.z = s[(size_t)(k + 2) * 512 + nc];
    v.w = s[(size_t)(k + 3) * 512 + nc];
    *reinterpret_cast<float4*>(&dst[(size_t)idx * 4]) = v;
}

// ---------------------------------------------------------------------------
// Embedding gather -> bf16 rows [t*128+b][512]
// ---------------------------------------------------------------------------
__global__ void __launch_bounds__(256) k_embed16(const int* __restrict__ tok,
                                                 const float* __restrict__ emb,
                                                 unsigned short* __restrict__ xe){
    int g = blockIdx.x * 256 + threadIdx.x;   // 245760 granules of 8
    int e8 = (g & 63) * 8;
    int b  = (g >> 6) & 127;
    int t  = g >> 13;
    int id = tok[b * T_ + t];
    const float4 v0 = *reinterpret_cast<const float4*>(emb + (size_t)id * E_ + e8);
    const float4 v1 = *reinterpret_cast<const float4*>(emb + (size_t)id * E_ + e8 + 4);
    u16x8 o;
    o[0] = f2bf(v0.x); o[1] = f2bf(v0.y); o[2] = f2bf(v0.z); o[3] = f2bf(v0.w);
    o[4] = f2bf(v1.x); o[5] = f2bf(v1.y); o[6] = f2bf(v1.z); o[7] = f2bf(v1.w);
    *reinterpret_cast<u16x8*>(&xe[((size_t)t * B_ + b) * 512 + e8]) = o;
}

// ---------------------------------------------------------------------------
// h0 partial GEMM (vgg @ W_in), split-F
// ---------------------------------------------------------------------------
__global__ void __launch_bounds__(256) k_h0p(const float* __restrict__ vgg,
                                             const float* __restrict__ Win,
                                             float* __restrict__ part){
    __shared__ float a[8][520];
    const int b0 = blockIdx.x * 8;
    const int fs = blockIdx.y;
    const int f0 = fs * 512;
    const int tid = threadIdx.x;
    for (int q = 0; q < 4; ++q){
        int idx = tid + q * 256;
        int r = idx >> 7, c4 = (idx & 127) * 4;
        *reinterpret_cast<float4*>(&a[r][c4]) =
            *reinterpret_cast<const float4*>(vgg + (size_t)(b0 + r) * F_ + f0 + c4);
    }
    __syncthreads();
    float acc[8][2];
    #pragma unroll
    for (int i = 0; i < 8; ++i){ acc[i][0] = 0.f; acc[i][1] = 0.f; }
    for (int f = 0; f < 512; f += 4){
        float w0a = Win[(size_t)(f0 + f    ) * H_ + tid];
        float w0b = Win[(size_t)(f0 + f    ) * H_ + tid + 256];
        float w1a = Win[(size_t)(f0 + f + 1) * H_ + tid];
        float w1b = Win[(size_t)(f0 + f + 1) * H_ + tid + 256];
        float w2a = Win[(size_t)(f0 + f + 2) * H_ + tid];
        float w2b = Win[(size_t)(f0 + f + 2) * H_ + tid + 256];
        float w3a = Win[(size_t)(f0 + f + 3) * H_ + tid];
        float w3b = Win[(size_t)(f0 + f + 3) * H_ + tid + 256];
        #pragma unroll
        for (int i = 0; i < 8; ++i){
            const float4 av = *reinterpret_cast<const float4*>(&a[i][f]);
            acc[i][0] += av.x * w0a + av.y * w1a + av.z * w2a + av.w * w3a;
            acc[i][1] += av.x * w0b + av.y * w1b + av.z * w2b + av.w * w3b;
        }
    }
    for (int i = 0; i < 8; ++i){
        part[((size_t)fs * B_ + b0 + i) * H_ + tid      ] = acc[i][0];
        part[((size_t)fs * B_ + b0 + i) * H_ + tid + 256] = acc[i][1];
    }
}

// reduce partials + bias + tanh -> h0 state (both layers), zero barrier
__global__ void __launch_bounds__(256) k_h0r(const float* __restrict__ part,
                                             const float* __restrict__ b_in,
                                             float* __restrict__ h0a,
                                             float* __restrict__ h1a,
                                             unsigned* __restrict__ bar){
    int g  = blockIdx.x * 256 + threadIdx.x;
    int i4 = g * 4;
    float4 s = *reinterpret_cast<const float4*>(part + i4);
    for (int fs = 1; fs < 8; ++fs){
        const float4 p = *reinterpret_cast<const float4*>(part + (size_t)fs * 65536 + i4);
        s.x += p.x; s.y += p.y; s.z += p.z; s.w += p.w;
    }
    int h = i4 & 511;
    const float4 bi = *reinterpret_cast<const float4*>(b_in + h);
    float4 o;
    o.x = tanhf(s.x + bi.x); o.y = tanhf(s.y + bi.y);
    o.z = tanhf(s.z + bi.z); o.w = tanhf(s.w + bi.w);
    *reinterpret_cast<float4*>(h0a + i4) = o;
    *reinterpret_cast<float4*>(h1a + i4) = o;
    if (blockIdx.x == 0 && threadIdx.x == 0){ bar[0] = 0u; bar[1] = 0u; }
}

// ---------------------------------------------------------------------------
// gx = xemb16 @ WxT^T + bias  (bf16 MFMA, f32 out)  -> [3840][1536]
// cols 0:512 u_x+bu0, 512:1024 r_x+br0, 1024:1536 c_x+bc0
// ---------------------------------------------------------------------------
__global__ void __launch_bounds__(256) k_gx(const unsigned short* __restrict__ xe,
                                            const unsigned short* __restrict__ WxT,
                                            const float* __restrict__ bu0,
                                            const float* __restrict__ br0,
                                            const float* __restrict__ bc0,
                                            float* __restrict__ gx){
    __shared__ unsigned short al[128 * 72];
    __shared__ unsigned short bl[128 * 72];
    const int n0 = blockIdx.x * 128;   // 12
    const int m0 = blockIdx.y * 128;   // 30
    const int tid = threadIdx.x;
    const int lane = tid & 63;
    const int wid = tid >> 6;
    const int wm = (wid >> 1) * 64;
    const int wn = (wid & 1) * 64;
    f32x4 acc[4][4];
    #pragma unroll
    for (int i = 0; i < 4; ++i)
        #pragma unroll
        for (int jj = 0; jj < 4; ++jj)
            acc[i][jj] = (f32x4){0.f, 0.f, 0.f, 0.f};

    for (int c = 0; c < 8; ++c){
        const int k0 = c * 64;
        __syncthreads();
        #pragma unroll
        for (int q = 0; q < 4; ++q){
            const int li = tid + q * 256;
            const int row = li >> 3;
            const int seg = li & 7;
            *reinterpret_cast<u16x8*>(&al[row * 72 + seg * 8]) =
                *reinterpret_cast<const u16x8*>(xe + (size_t)(m0 + row) * 512 + k0 + seg * 8);
            *reinterpret_cast<u16x8*>(&bl[row * 72 + seg * 8]) =
                *reinterpret_cast<const u16x8*>(WxT + (size_t)(n0 + row) * 512 + k0 + seg * 8);
        }
        __syncthreads();
        #pragma unroll
        for (int ks = 0; ks < 2; ++ks){
            bf16x8 af[4], bfr[4];
            #pragma unroll
            for (int f = 0; f < 4; ++f){
                af[f]  = *reinterpret_cast<const bf16x8*>(
                    &al[(wm + f * 16 + (lane & 15)) * 72 + ks * 32 + (lane >> 4) * 8]);
                bfr[f] = *reinterpret_cast<const bf16x8*>(
                    &bl[(wn + f * 16 + (lane & 15)) * 72 + ks * 32 + (lane >> 4) * 8]);
            }
            #pragma unroll
            for (int fm = 0; fm < 4; ++fm)
                #pragma unroll
                for (int fn = 0; fn < 4; ++fn)
                    acc[fm][fn] = __builtin_amdgcn_mfma_f32_16x16x32_bf16(
                        af[fm], bfr[fn], acc[fm][fn], 0, 0, 0);
        }
    }
    #pragma unroll
    for (int fm = 0; fm < 4; ++fm){
        #pragma unroll
        for (int fn = 0; fn < 4; ++fn){
            const int cl = n0 + wn + fn * 16 + (lane & 15);
            const float bo = (cl < 512) ? bu0[cl] : (cl < 1024) ? br0[cl - 512] : bc0[cl - 1024];
            #pragma unroll
            for (int mi = 0; mi < 4; ++mi){
                const int m = m0 + wm + fm * 16 + (lane >> 4) * 4 + mi;
                gx[(size_t)m * 1536 + cl] = acc[fm][fn][mi] + bo;
            }
        }
    }
}

// ---------------------------------------------------------------------------
// Persistent cooperative recurrence kernel
// ---------------------------------------------------------------------------
struct RecurArgs {
    const float* gx;
    const float* Wg0; const float* Wc0; const float* Wg1; const float* Wc1;
    const float* bu1; const float* br1; const float* bc1;
    float* h0a; float* h0b; float* h1a; float* h1b;
    float* ur0; float* ur1;
    unsigned short* xs16;
    float* fsout;
    unsigned* bar;
};

__device__ __forceinline__ void gridbar(unsigned* bar, int target){
    __syncthreads();
    if (threadIdx.x == 0){
        __threadfence();
        unsigned arr = __hip_atomic_fetch_add(&bar[0], 1u, __ATOMIC_ACQ_REL,
                                              __HIP_MEMORY_SCOPE_AGENT) + 1u;
        if (arr == (unsigned)(256 * target)){
            __hip_atomic_store(&bar[1], (unsigned)target, __ATOMIC_RELEASE,
                               __HIP_MEMORY_SCOPE_AGENT);
        } else {
            while ((int)__hip_atomic_load(&bar[1], __ATOMIC_ACQUIRE,
                                          __HIP_MEMORY_SCOPE_AGENT) < target){
                __builtin_amdgcn_s_sleep(2);
            }
        }
    }
    __syncthreads();
}

template<int K>
__device__ __forceinline__ float2 core(const float* __restrict__ Wp,
                                       const float* as_, int n0, int lane, int w){
    float a0a = 0.f, a0b = 0.f, a1a = 0.f, a1b = 0.f;
    const float* bp = Wp + ((size_t)(n0 >> 6) * (K >> 2)) * 256 + lane * 4;
    const float* ar0 = as_ + (w * 2 + 0) * K;
    const float* ar1 = as_ + (w * 2 + 1) * K;
    #pragma unroll 4
    for (int kq = 0; kq < (K >> 2); ++kq){
        const float4 bv  = *reinterpret_cast<const float4*>(bp + (size_t)kq * 256);
        const float4 av0 = *reinterpret_cast<const float4*>(ar0 + kq * 4);
        const float4 av1 = *reinterpret_cast<const float4*>(ar1 + kq * 4);
        a0a = fmaf(av0.x, bv.x, a0a); a0b = fmaf(av0.y, bv.y, a0b);
        a0a = fmaf(av0.z, bv.z, a0a); a0b = fmaf(av0.w, bv.w, a0b);
        a1a = fmaf(av1.x, bv.x, a1a); a1b = fmaf(av1.y, bv.y, a1b);
        a1a = fmaf(av1.z, bv.z, a1a); a1b = fmaf(av1.w, bv.w, a1b);
    }
    float2 r; r.x = a0a + a0b; r.y = a1a + a1b; return r;
}

__global__ void __launch_bounds__(256) k_recur(RecurArgs A){
    __shared__ float as_[8192];
    const int blk = blockIdx.x, tid = threadIdx.x;
    const int lane = tid & 63, w = tid >> 6;
    int gen = 0;
    for (int t = 0; t < T_; ++t){
        float* h0old = (t & 1) ? A.h0b : A.h0a;
        float* h0new = (t & 1) ? A.h0a : A.h0b;
        float* h1old = (t & 1) ? A.h1b : A.h1a;
        float* h1new = (t & 1) ? A.h1a : A.h1b;
        const float* gxt = A.gx + (size_t)t * 196608;

        // ---- P1: ur0 = sigmoid(h0old @ Wg0h + gx[:,0:1024]) ----
        {
            const int m0 = (blk >> 4) * 8, n0 = (blk & 15) * 64;
            for (int q = 0; q < 4; ++q){
                int idx = tid + q * 256, r = idx >> 7, c4 = (idx & 127) << 2;
                *reinterpret_cast<float4*>(&as_[r * 512 + c4]) =
                    *reinterpret_cast<const float4*>(&h0old[(size_t)(m0 + r) * 512 + c4]);
            }
            __syncthreads();
            float2 s = core<512>(A.Wg0, as_, n0, lane, w);
            const int n = n0 + lane;
            #pragma unroll
            for (int i = 0; i < 2; ++i){
                const int m = m0 + w * 2 + i;
                float pre = ((i == 0) ? s.x : s.y) + gxt[(size_t)m * 1536 + n];
                A.ur0[(size_t)m * 1024 + n] = 1.f / (1.f + __expf(-pre));
            }
        }
        gridbar(A.bar, ++gen);

        // ---- P2: h0new = u*h + (1-u)*tanh((r*h)@Wc0h + gx[:,1024:1536]) ----
        if (blk < 128){
            const int m0 = (blk >> 3) * 8, n0 = (blk & 7) * 64;
            for (int q = 0; q < 4; ++q){
                int idx = tid + q * 256, r = idx >> 7, c4 = (idx & 127) << 2;
                const float4 rv = *reinterpret_cast<const float4*>(
                    &A.ur0[(size_t)(m0 + r) * 1024 + 512 + c4]);
                const float4 hv = *reinterpret_cast<const float4*>(
                    &h0old[(size_t)(m0 + r) * 512 + c4]);
                float4 p; p.x = rv.x*hv.x; p.y = rv.y*hv.y; p.z = rv.z*hv.z; p.w = rv.w*hv.w;
                *reinterpret_cast<float4*>(&as_[r * 512 + c4]) = p;
            }
            __syncthreads();
            float2 s = core<512>(A.Wc0, as_, n0, lane, w);
            const int n = n0 + lane;
            #pragma unroll
            for (int i = 0; i < 2; ++i){
                const int m = m0 + w * 2 + i;
                float cand = tanhf(((i == 0) ? s.x : s.y) + gxt[(size_t)m * 1536 + 1024 + n]);
                float u = A.ur0[(size_t)m * 1024 + n];
                float h = h0old[(size_t)m * 512 + n];
                float h2 = u * h + (1.f - u) * cand;
                h0new[(size_t)m * 512 + n] = h2;
                if (t == T_ - 1) A.fsout[(size_t)m * 512 + n] = h2;
            }
        }
        gridbar(A.bar, ++gen);

        // ---- P3: ur1 = sigmoid([h0new|h1old] @ Wg1 + b) ----
        {
            const int m0 = (blk >> 4) * 8, n0 = (blk & 15) * 64;
            for (int q = 0; q < 8; ++q){
                int idx = tid + q * 256, r = idx >> 8, c4 = (idx & 255) << 2;
                float4 v;
                if (c4 < 512) v = *reinterpret_cast<const float4*>(
                                    &h0new[(size_t)(m0 + r) * 512 + c4]);
                else          v = *reinterpret_cast<const float4*>(
                                    &h1old[(size_t)(m0 + r) * 512 + (c4 - 512)]);
                *reinterpret_cast<float4*>(&as_[r * 1024 + c4]) = v;
            }
            __syncthreads();
            float2 s = core<1024>(A.Wg1, as_, n0, lane, w);
            const int n = n0 + lane;
            const float bias = (n < 512) ? A.bu1[n] : A.br1[n - 512];
            #pragma unroll
            for (int i = 0; i < 2; ++i){
                const int m = m0 + w * 2 + i;
                float pre = ((i == 0) ? s.x : s.y) + bias;
                A.ur1[(size_t)m * 1024 + n] = 1.f / (1.f + __expf(-pre));
            }
        }
        gridbar(A.bar, ++gen);

        // ---- P4: h1new = u*h + (1-u)*tanh([h0new|r*h1old] @ Wc1 + bc1) ----
        if (blk < 128){
            const int m0 = (blk >> 3) * 8, n0 = (blk & 7) * 64;
            for (int q = 0; q < 8; ++q){
                int idx = tid + q * 256, r = idx >> 8, c4 = (idx & 255) << 2;
                float4 v;
                if (c4 < 512){
                    v = *reinterpret_cast<const float4*>(&h0new[(size_t)(m0 + r) * 512 + c4]);
                } else {
                    const float4 rv = *reinterpret_cast<const float4*>(
                        &A.ur1[(size_t)(m0 + r) * 1024 + 512 + (c4 - 512)]);
                    const float4 hv = *reinterpret_cast<const float4*>(
                        &h1old[(size_t)(m0 + r) * 512 + (c4 - 512)]);
                    v.x = rv.x*hv.x; v.y = rv.y*hv.y; v.z = rv.z*hv.z; v.w = rv.w*hv.w;
                }
                *reinterpret_cast<float4*>(&as_[r * 1024 + c4]) = v;
            }
            __syncthreads();
            float2 s = core<1024>(A.Wc1, as_, n0, lane, w);
            const int n = n0 + lane;
            const float bias = A.bc1[n];
            #pragma unroll
            for (int i = 0; i < 2; ++i){
                const int m = m0 + w * 2 + i;
                float cand = tanhf(((i == 0) ? s.x : s.y) + bias);
                float u = A.ur1[(size_t)m * 1024 + n];
                float h = h1old[(size_t)m * 512 + n];
                float h2 = u * h + (1.f - u) * cand;
                h1new[(size_t)m * 512 + n] = h2;
                A.xs16[((size_t)t * B_ + m) * 512 + n] = f2bf(h2);
                if (t == T_ - 1) A.fsout[65536 + (size_t)m * 512 + n] = h2;
            }
        }
        gridbar(A.bar, ++gen);
    }
}

// ---------------------------------------------------------------------------
// Logits GEMM (unchanged from round 0)
// ---------------------------------------------------------------------------
__global__ void __launch_bounds__(256) k_logits(const unsigned short* __restrict__ xs16,
                                                const unsigned short* __restrict__ WbT,
                                                const float* __restrict__ b_out,
                                                float* __restrict__ out){
    __shared__ unsigned short al[128 * 72];
    __shared__ unsigned short bl[128 * 72];
    const int n0 = blockIdx.x * 128;
    const int t  = blockIdx.y;
    const int m0 = t * 128;
    const int tid = threadIdx.x;
    const int lane = tid & 63;
    const int wid = tid >> 6;
    const int wm = (wid >> 1) * 64;
    const int wn = (wid & 1) * 64;
    f32x4 acc[4][4];
    #pragma unroll
    for (int i = 0; i < 4; ++i)
        #pragma unroll
        for (int jj = 0; jj < 4; ++jj)
            acc[i][jj] = (f32x4){0.f, 0.f, 0.f, 0.f};

    for (int c = 0; c < 8; ++c){
        const int k0 = c * 64;
        __syncthreads();
        #pragma unroll
        for (int q = 0; q < 4; ++q){
            const int li = tid + q * 256;
            const int row = li >> 3;
            const int seg = li & 7;
            *reinterpret_cast<u16x8*>(&al[row * 72 + seg * 8]) =
                *reinterpret_cast<const u16x8*>(xs16 + (size_t)(m0 + row) * 512 + k0 + seg * 8);
            *reinterpret_cast<u16x8*>(&bl[row * 72 + seg * 8]) =
                *reinterpret_cast<const u16x8*>(WbT + (size_t)(n0 + row) * 512 + k0 + seg * 8);
        }
        __syncthreads();
        #pragma unroll
        for (int ks = 0; ks < 2; ++ks){
            bf16x8 af[4], bfr[4];
            #pragma unroll
            for (int f = 0; f < 4; ++f){
                af[f]  = *reinterpret_cast<const bf16x8*>(
                    &al[(wm + f * 16 + (lane & 15)) * 72 + ks * 32 + (lane >> 4) * 8]);
                bfr[f] = *reinterpret_cast<const bf16x8*>(
                    &bl[(wn + f * 16 + (lane & 15)) * 72 + ks * 32 + (lane >> 4) * 8]);
            }
            #pragma unroll
            for (int fm = 0; fm < 4; ++fm)
                #pragma unroll
                for (int fn = 0; fn < 4; ++fn)
                    acc[fm][fn] = __builtin_amdgcn_mfma_f32_16x16x32_bf16(
                        af[fm], bfr[fn], acc[fm][fn], 0, 0, 0);
        }
    }
    #pragma unroll
    for (int fm = 0; fm < 4; ++fm){
        #pragma unroll
        for (int fn = 0; fn < 4; ++fn){
            const int v = n0 + wn + fn * 16 + (lane & 15);
            if (v < V_){
                const float bo = b_out[v];
                #pragma unroll
                for (int mi = 0; mi < 4; ++mi){
                    const int b = wm + fm * 16 + (lane >> 4) * 4 + mi;
                    out[(size_t)b * (T_ * V_) + (size_t)t * V_ + v] = acc[fm][fn][mi] + bo;
                }
            }
        }
    }
}

// ---------------------------------------------------------------------------
extern "C" void kernel_launch(void* const* d_in, const int* in_sizes, int n_in,
                              void* d_out, int out_size, void* d_ws, size_t ws_size,
                              hipStream_t stream){
    const float* vgg  = (const float*)d_in[0];
    const int*   tok  = (const int*)  d_in[1];
    const float* emb  = (const float*)d_in[2];
    const float* Win  = (const float*)d_in[3];
    const float* bin  = (const float*)d_in[4];
    const float* Wu   = (const float*)d_in[5];
    const float* bu   = (const float*)d_in[6];
    const float* Wr   = (const float*)d_in[7];
    const float* br   = (const float*)d_in[8];
    const float* Wc   = (const float*)d_in[9];
    const float* bc   = (const float*)d_in[10];
    const float* Wout = (const float*)d_in[11];
    const float* bout = (const float*)d_in[12];
    float* out = (float*)d_out;

    // f32 workspace offsets (in floats)
    float* ws = (float*)d_ws;
    float* h0a  = ws;
    float* h0b  = ws + 65536;
    float* h1a  = ws + 131072;
    float* h1b  = ws + 196608;
    float* ur0  = ws + 262144;
    float* ur1  = ws + 393216;
    float* gx   = ws + 524288;     // [3840][1536]
    float* h0p  = ws + 6422528;    // [8][128][512]
    float* Wg0  = ws + 6946816;    // packed [1024n][512k]
    float* Wc0  = ws + 7471104;    // packed [512n][512k]
    float* Wg1  = ws + 7733248;    // packed [1024n][1024k]
    float* Wc1  = ws + 8781824;    // packed [512n][1024k]
    unsigned* bar = (unsigned*)(ws + 9306112);
    // u16 areas
    unsigned short* xs16   = (unsigned short*)((char*)d_ws + 37224960);  // [3840][512]
    unsigned short* WbT    = (unsigned short*)((char*)d_ws + 41157120);  // [VPAD][512]
    unsigned short* xemb16 = (unsigned short*)((char*)d_ws + 51511808);  // [3840][512]
    unsigned short* WxT    = (unsigned short*)((char*)d_ws + 55443968);  // [1536][512]

    const float* Wu0 = Wu, *Wu1 = Wu + 524288;
    const float* Wr0 = Wr, *Wr1 = Wr + 524288;
    const float* Wc0s = Wc, *Wc1s = Wc + 524288;

    // ---- setup (t-independent) ----
    k_castWT<<<dim3(158, 8), dim3(256), 0, stream>>>(Wout, WbT);
    k_castWxT<<<dim3(8, 8), dim3(256), 0, stream>>>(Wu0,  WxT);
    k_castWxT<<<dim3(8, 8), dim3(256), 0, stream>>>(Wr0,  WxT + 262144);
    k_castWxT<<<dim3(8, 8), dim3(256), 0, stream>>>(Wc0s, WxT + 524288);
    k_embed16<<<dim3(960), dim3(256), 0, stream>>>(tok, emb, xemb16);
    // packed recurrence weights
    k_prepW<<<dim3(512),  dim3(256), 0, stream>>>(Wg0, Wu0,  Wr0,  512, 128);
    k_prepW<<<dim3(256),  dim3(256), 0, stream>>>(Wc0, Wc0s, Wc0s, 512, 128);
    k_prepW<<<dim3(1024), dim3(256), 0, stream>>>(Wg1, Wu1,  Wr1,  0,   256);
    k_prepW<<<dim3(512),  dim3(256), 0, stream>>>(Wc1, Wc1s, Wc1s, 0,   256);
    k_h0p<<<dim3(16, 8), dim3(256), 0, stream>>>(vgg, Win, h0p);
    k_h0r<<<dim3(64), dim3(256), 0, stream>>>(h0p, bin, h0a, h1a, bar);
    k_gx<<<dim3(12, 30), dim3(256), 0, stream>>>(xemb16, WxT, bu, br, bc, gx);

    // ---- persistent cooperative recurrence ----
    RecurArgs ra;
    ra.gx = gx; ra.Wg0 = Wg0; ra.Wc0 = Wc0; ra.Wg1 = Wg1; ra.Wc1 = Wc1;
    ra.bu1 = bu + 512; ra.br1 = br + 512; ra.bc1 = bc + 512;
    ra.h0a = h0a; ra.h0b = h0b; ra.h1a = h1a; ra.h1b = h1b;
    ra.ur0 = ur0; ra.ur1 = ur1;
    ra.xs16 = xs16; ra.fsout = out + 38400000; ra.bar = bar;
    void* args[] = { &ra };
    hipLaunchCooperativeKernel((const void*)k_recur, dim3(256), dim3(256), args, 0, stream);

    // ---- logits ----
    k_logits<<<dim3(79, 30), dim3(256), 0, stream>>>(xs16, WbT, bout, out);
}

// Round 3
// 7529.237 us; speedup vs baseline: 1.9080x; 1.9080x over previous
//
#include <hip/hip_runtime.h>
#include <hip/hip_bf16.h>

// Problem constants
#define B_   128
#define T_   30
#define V_   10000
#define E_   512
#define H_   512
#define F_   4096
#define L_   2
#define VPAD 10112   // 79 * 128

typedef __attribute__((ext_vector_type(4))) float f32x4;
typedef __attribute__((ext_vector_type(8))) __bf16 bf16x8;
typedef __attribute__((ext_vector_type(8))) unsigned short u16x8;

__device__ __forceinline__ unsigned short f2bf(float x){
    unsigned int u = __float_as_uint(x);
    unsigned int r = (u + 0x7FFFu + ((u >> 16) & 1u)) >> 16;
    return (unsigned short)r;
}

// ---------------------------------------------------------------------------
// W_out [512][10000] f32  ->  WbT [VPAD][512] bf16 (transposed, zero-padded)
// ---------------------------------------------------------------------------
__global__ void __launch_bounds__(256) k_castWT(const float* __restrict__ W,
                                                unsigned short* __restrict__ WbT){
    __shared__ float tile[64][65];
    const int n0 = blockIdx.x * 64;
    const int k0 = blockIdx.y * 64;
    const int tid = threadIdx.x;
    for (int q = 0; q < 16; ++q){
        int idx = tid + q * 256;
        int kk = idx >> 6, nn = idx & 63;
        int n = n0 + nn;
        tile[kk][nn] = (n < V_) ? W[(size_t)(k0 + kk) * V_ + n] : 0.f;
    }
    __syncthreads();
    for (int q = 0; q < 16; ++q){
        int idx = tid + q * 256;
        int nn = idx >> 6, kk = idx & 63;
        WbT[(size_t)(n0 + nn) * 512 + k0 + kk] = f2bf(tile[kk][nn]);
    }
}

// ---------------------------------------------------------------------------
// x-part weights: W{u,r,c}[0][0:512][:] -> WxT section [512][512] bf16 transposed
// ---------------------------------------------------------------------------
__global__ void __launch_bounds__(256) k_castWxT(const float* __restrict__ src,
                                                 unsigned short* __restrict__ dst){
    __shared__ float tile[64][65];
    const int n0 = blockIdx.x * 64;
    const int k0 = blockIdx.y * 64;
    const int tid = threadIdx.x;
    for (int q = 0; q < 16; ++q){
        int idx = tid + q * 256;
        int kk = idx >> 6, nn = idx & 63;
        tile[kk][nn] = src[(size_t)(k0 + kk) * 512 + n0 + nn];
    }
    __syncthreads();
    for (int q = 0; q < 16; ++q){
        int idx = tid + q * 256;
        int nn = idx >> 6, kk = idx & 63;
        dst[(size_t)(n0 + nn) * 512 + k0 + kk] = f2bf(tile[kk][nn]);
    }
}

// ---------------------------------------------------------------------------
// Pack recurrence weights f32 -> lane-major tiles
// ---------------------------------------------------------------------------
__global__ void __launch_bounds__(256) k_prepW(float* __restrict__ dst,
                                               const float* __restrict__ srcA,
                                               const float* __restrict__ srcB,
                                               int koff, int Kq){
    const int idx = blockIdx.x * 256 + threadIdx.x;
    const int l = idx & 63;
    const int gk = idx >> 6;
    const int kq = gk % Kq;
    const int g  = gk / Kq;
    const int n = g * 64 + l;
    const float* s = (n < 512) ? srcA : srcB;
    const int nc = n & 511;
    const int k = koff + kq * 4;
    float4 v;
    v.x = s[(size_t)(k    ) * 512 + nc];
    v.y = s[(size_t)(k + 1) * 512 + nc];
    v.z = s[(size_t)(k + 2) * 512 + nc];
    v.w = s[(size_t)(k + 3) * 512 + nc];
    *reinterpret_cast<float4*>(&dst[(size_t)idx * 4]) = v;
}

// ---------------------------------------------------------------------------
// Embedding gather -> bf16 rows [t*128+b][512]
// ---------------------------------------------------------------------------
__global__ void __launch_bounds__(256) k_embed16(const int* __restrict__ tok,
                                                 const float* __restrict__ emb,
                                                 unsigned short* __restrict__ xe){
    int g = blockIdx.x * 256 + threadIdx.x;
    int e8 = (g & 63) * 8;
    int b  = (g >> 6) & 127;
    int t  = g >> 13;
    int id = tok[b * T_ + t];
    const float4 v0 = *reinterpret_cast<const float4*>(emb + (size_t)id * E_ + e8);
    const float4 v1 = *reinterpret_cast<const float4*>(emb + (size_t)id * E_ + e8 + 4);
    u16x8 o;
    o[0] = f2bf(v0.x); o[1] = f2bf(v0.y); o[2] = f2bf(v0.z); o[3] = f2bf(v0.w);
    o[4] = f2bf(v1.x); o[5] = f2bf(v1.y); o[6] = f2bf(v1.z); o[7] = f2bf(v1.w);
    *reinterpret_cast<u16x8*>(&xe[((size_t)t * B_ + b) * 512 + e8]) = o;
}

// ---------------------------------------------------------------------------
// h0 partial GEMM (vgg @ W_in), split-F
// ---------------------------------------------------------------------------
__global__ void __launch_bounds__(256) k_h0p(const float* __restrict__ vgg,
                                             const float* __restrict__ Win,
                                             float* __restrict__ part){
    __shared__ float a[8][520];
    const int b0 = blockIdx.x * 8;
    const int fs = blockIdx.y;
    const int f0 = fs * 512;
    const int tid = threadIdx.x;
    for (int q = 0; q < 4; ++q){
        int idx = tid + q * 256;
        int r = idx >> 7, c4 = (idx & 127) * 4;
        *reinterpret_cast<float4*>(&a[r][c4]) =
            *reinterpret_cast<const float4*>(vgg + (size_t)(b0 + r) * F_ + f0 + c4);
    }
    __syncthreads();
    float acc[8][2];
    #pragma unroll
    for (int i = 0; i < 8; ++i){ acc[i][0] = 0.f; acc[i][1] = 0.f; }
    for (int f = 0; f < 512; f += 4){
        float w0a = Win[(size_t)(f0 + f    ) * H_ + tid];
        float w0b = Win[(size_t)(f0 + f    ) * H_ + tid + 256];
        float w1a = Win[(size_t)(f0 + f + 1) * H_ + tid];
        float w1b = Win[(size_t)(f0 + f + 1) * H_ + tid + 256];
        float w2a = Win[(size_t)(f0 + f + 2) * H_ + tid];
        float w2b = Win[(size_t)(f0 + f + 2) * H_ + tid + 256];
        float w3a = Win[(size_t)(f0 + f + 3) * H_ + tid];
        float w3b = Win[(size_t)(f0 + f + 3) * H_ + tid + 256];
        #pragma unroll
        for (int i = 0; i < 8; ++i){
            const float4 av = *reinterpret_cast<const float4*>(&a[i][f]);
            acc[i][0] += av.x * w0a + av.y * w1a + av.z * w2a + av.w * w3a;
            acc[i][1] += av.x * w0b + av.y * w1b + av.z * w2b + av.w * w3b;
        }
    }
    for (int i = 0; i < 8; ++i){
        part[((size_t)fs * B_ + b0 + i) * H_ + tid      ] = acc[i][0];
        part[((size_t)fs * B_ + b0 + i) * H_ + tid + 256] = acc[i][1];
    }
}

// reduce partials + bias + tanh -> h0 state (both layers)
__global__ void __launch_bounds__(256) k_h0r(const float* __restrict__ part,
                                             const float* __restrict__ b_in,
                                             float* __restrict__ h0a,
                                             float* __restrict__ h1a){
    int g  = blockIdx.x * 256 + threadIdx.x;
    int i4 = g * 4;
    float4 s = *reinterpret_cast<const float4*>(part + i4);
    for (int fs = 1; fs < 8; ++fs){
        const float4 p = *reinterpret_cast<const float4*>(part + (size_t)fs * 65536 + i4);
        s.x += p.x; s.y += p.y; s.z += p.z; s.w += p.w;
    }
    int h = i4 & 511;
    const float4 bi = *reinterpret_cast<const float4*>(b_in + h);
    float4 o;
    o.x = tanhf(s.x + bi.x); o.y = tanhf(s.y + bi.y);
    o.z = tanhf(s.z + bi.z); o.w = tanhf(s.w + bi.w);
    *reinterpret_cast<float4*>(h0a + i4) = o;
    *reinterpret_cast<float4*>(h1a + i4) = o;
}

// zero the barrier flag region (runs AFTER k_h0r; aliases h0p scratch)
__global__ void __launch_bounds__(256) k_zerobar(unsigned* __restrict__ flags){
    int idx = blockIdx.x * 256 + threadIdx.x;
    if (idx < 4352) flags[idx] = 0u;
}

// ---------------------------------------------------------------------------
// gx = xemb16 @ WxT^T + bias  (bf16 MFMA, f32 out)  -> [3840][1536]
// ---------------------------------------------------------------------------
__global__ void __launch_bounds__(256) k_gx(const unsigned short* __restrict__ xe,
                                            const unsigned short* __restrict__ WxT,
                                            const float* __restrict__ bu0,
                                            const float* __restrict__ br0,
                                            const float* __restrict__ bc0,
                                            float* __restrict__ gx){
    __shared__ unsigned short al[128 * 72];
    __shared__ unsigned short bl[128 * 72];
    const int n0 = blockIdx.x * 128;
    const int m0 = blockIdx.y * 128;
    const int tid = threadIdx.x;
    const int lane = tid & 63;
    const int wid = tid >> 6;
    const int wm = (wid >> 1) * 64;
    const int wn = (wid & 1) * 64;
    f32x4 acc[4][4];
    #pragma unroll
    for (int i = 0; i < 4; ++i)
        #pragma unroll
        for (int jj = 0; jj < 4; ++jj)
            acc[i][jj] = (f32x4){0.f, 0.f, 0.f, 0.f};

    for (int c = 0; c < 8; ++c){
        const int k0 = c * 64;
        __syncthreads();
        #pragma unroll
        for (int q = 0; q < 4; ++q){
            const int li = tid + q * 256;
            const int row = li >> 3;
            const int seg = li & 7;
            *reinterpret_cast<u16x8*>(&al[row * 72 + seg * 8]) =
                *reinterpret_cast<const u16x8*>(xe + (size_t)(m0 + row) * 512 + k0 + seg * 8);
            *reinterpret_cast<u16x8*>(&bl[row * 72 + seg * 8]) =
                *reinterpret_cast<const u16x8*>(WxT + (size_t)(n0 + row) * 512 + k0 + seg * 8);
        }
        __syncthreads();
        #pragma unroll
        for (int ks = 0; ks < 2; ++ks){
            bf16x8 af[4], bfr[4];
            #pragma unroll
            for (int f = 0; f < 4; ++f){
                af[f]  = *reinterpret_cast<const bf16x8*>(
                    &al[(wm + f * 16 + (lane & 15)) * 72 + ks * 32 + (lane >> 4) * 8]);
                bfr[f] = *reinterpret_cast<const bf16x8*>(
                    &bl[(wn + f * 16 + (lane & 15)) * 72 + ks * 32 + (lane >> 4) * 8]);
            }
            #pragma unroll
            for (int fm = 0; fm < 4; ++fm)
                #pragma unroll
                for (int fn = 0; fn < 4; ++fn)
                    acc[fm][fn] = __builtin_amdgcn_mfma_f32_16x16x32_bf16(
                        af[fm], bfr[fn], acc[fm][fn], 0, 0, 0);
        }
    }
    #pragma unroll
    for (int fm = 0; fm < 4; ++fm){
        #pragma unroll
        for (int fn = 0; fn < 4; ++fn){
            const int cl = n0 + wn + fn * 16 + (lane & 15);
            const float bo = (cl < 512) ? bu0[cl] : (cl < 1024) ? br0[cl - 512] : bc0[cl - 1024];
            #pragma unroll
            for (int mi = 0; mi < 4; ++mi){
                const int m = m0 + wm + fm * 16 + (lane >> 4) * 4 + mi;
                gx[(size_t)m * 1536 + cl] = acc[fm][fn][mi] + bo;
            }
        }
    }
}

// ---------------------------------------------------------------------------
// Persistent cooperative recurrence kernel
// ---------------------------------------------------------------------------
struct RecurArgs {
    const float* gx;
    const float* Wg0; const float* Wc0; const float* Wg1; const float* Wc1;
    const float* bu1; const float* br1; const float* bc1;
    float* h0a; float* h0b; float* h1a; float* h1b;
    float* ur0; float* ur1;
    unsigned short* xs16;
    float* fsout;
    unsigned* flags;   // [256 * 16] arrival flags (64B-spaced) + go at [4096]
};

// Distributed-flag grid barrier: per-block arrival flags (no contention),
// block 0 aggregates with 256 parallel pollers, single 'go' broadcast.
__device__ __forceinline__ void gridbar(unsigned* flags, int gen){
    __syncthreads();
    unsigned* go = flags + 4096;
    if (blockIdx.x == 0){
        const int tid = threadIdx.x;
        if (tid > 0){   // poll arrival of blocks 1..255
            while ((int)__hip_atomic_load(&flags[tid * 16], __ATOMIC_ACQUIRE,
                                          __HIP_MEMORY_SCOPE_AGENT) < gen)
                __builtin_amdgcn_s_sleep(1);
        }
        __syncthreads();
        if (tid == 0)
            __hip_atomic_store(go, (unsigned)gen, __ATOMIC_RELEASE,
                               __HIP_MEMORY_SCOPE_AGENT);
    } else {
        if (threadIdx.x == 0){
            __hip_atomic_store(&flags[blockIdx.x * 16], (unsigned)gen,
                               __ATOMIC_RELEASE, __HIP_MEMORY_SCOPE_AGENT);
            while ((int)__hip_atomic_load(go, __ATOMIC_ACQUIRE,
                                          __HIP_MEMORY_SCOPE_AGENT) < gen)
                __builtin_amdgcn_s_sleep(2);
        }
    }
    __syncthreads();
}

// R rows per wave, K reduction; packed lane-major weights
template<int K, int R>
__device__ __forceinline__ void coreN(const float* __restrict__ Wp,
                                      const float* __restrict__ as_,
                                      int n0, int lane, int w,
                                      float* __restrict__ res){
    float acc[R][4];
    #pragma unroll
    for (int r = 0; r < R; ++r){
        acc[r][0] = 0.f; acc[r][1] = 0.f; acc[r][2] = 0.f; acc[r][3] = 0.f;
    }
    const float* bp = Wp + ((size_t)(n0 >> 6) * (K >> 2)) * 256 + lane * 4;
    #pragma unroll 8
    for (int kq = 0; kq < (K >> 2); ++kq){
        const float4 bv = *reinterpret_cast<const float4*>(bp + (size_t)kq * 256);
        #pragma unroll
        for (int r = 0; r < R; ++r){
            const float4 av = *reinterpret_cast<const float4*>(as_ + (w * R + r) * K + kq * 4);
            acc[r][0] = fmaf(av.x, bv.x, acc[r][0]);
            acc[r][1] = fmaf(av.y, bv.y, acc[r][1]);
            acc[r][2] = fmaf(av.z, bv.z, acc[r][2]);
            acc[r][3] = fmaf(av.w, bv.w, acc[r][3]);
        }
    }
    #pragma unroll
    for (int r = 0; r < R; ++r)
        res[r] = (acc[r][0] + acc[r][1]) + (acc[r][2] + acc[r][3]);
}

__global__ void __launch_bounds__(256) k_recur(RecurArgs A){
    __shared__ float as_[8192];
    const int blk = blockIdx.x, tid = threadIdx.x;
    const int lane = tid & 63, w = tid >> 6;
    int gen = 0;
    for (int t = 0; t < T_; ++t){
        float* h0old = (t & 1) ? A.h0b : A.h0a;
        float* h0new = (t & 1) ? A.h0a : A.h0b;
        float* h1old = (t & 1) ? A.h1b : A.h1a;
        float* h1new = (t & 1) ? A.h1a : A.h1b;
        const float* gxt = A.gx + (size_t)t * 196608;

        // ---- P1: ur0 = sigmoid(h0old @ Wg0h + gx[:,0:1024]) ----
        {
            const int m0 = (blk >> 4) * 8, n0 = (blk & 15) * 64;
            for (int q = 0; q < 4; ++q){
                int idx = tid + q * 256, r = idx >> 7, c4 = (idx & 127) << 2;
                *reinterpret_cast<float4*>(&as_[r * 512 + c4]) =
                    *reinterpret_cast<const float4*>(&h0old[(size_t)(m0 + r) * 512 + c4]);
            }
            __syncthreads();
            float s[2];
            coreN<512, 2>(A.Wg0, as_, n0, lane, w, s);
            const int n = n0 + lane;
            #pragma unroll
            for (int i = 0; i < 2; ++i){
                const int m = m0 + w * 2 + i;
                float pre = s[i] + gxt[(size_t)m * 1536 + n];
                A.ur0[(size_t)m * 1024 + n] = 1.f / (1.f + __expf(-pre));
            }
        }
        gridbar(A.flags, ++gen);

        // ---- P2: h0new = u*h + (1-u)*tanh((r*h)@Wc0h + gx[:,1024:1536]) ----
        {
            const int m0 = (blk >> 3) * 4, n0 = (blk & 7) * 64;
            for (int q = 0; q < 2; ++q){
                int idx = tid + q * 256, r = idx >> 7, c4 = (idx & 127) << 2;
                const float4 rv = *reinterpret_cast<const float4*>(
                    &A.ur0[(size_t)(m0 + r) * 1024 + 512 + c4]);
                const float4 hv = *reinterpret_cast<const float4*>(
                    &h0old[(size_t)(m0 + r) * 512 + c4]);
                float4 p; p.x = rv.x*hv.x; p.y = rv.y*hv.y; p.z = rv.z*hv.z; p.w = rv.w*hv.w;
                *reinterpret_cast<float4*>(&as_[r * 512 + c4]) = p;
            }
            __syncthreads();
            float s[1];
            coreN<512, 1>(A.Wc0, as_, n0, lane, w, s);
            const int n = n0 + lane;
            const int m = m0 + w;
            float cand = tanhf(s[0] + gxt[(size_t)m * 1536 + 1024 + n]);
            float u = A.ur0[(size_t)m * 1024 + n];
            float h = h0old[(size_t)m * 512 + n];
            float h2 = u * h + (1.f - u) * cand;
            h0new[(size_t)m * 512 + n] = h2;
            if (t == T_ - 1) A.fsout[(size_t)m * 512 + n] = h2;
        }
        gridbar(A.flags, ++gen);

        // ---- P3: ur1 = sigmoid([h0new|h1old] @ Wg1 + b) ----
        {
            const int m0 = (blk >> 4) * 8, n0 = (blk & 15) * 64;
            for (int q = 0; q < 8; ++q){
                int idx = tid + q * 256, r = idx >> 8, c4 = (idx & 255) << 2;
                float4 v;
                if (c4 < 512) v = *reinterpret_cast<const float4*>(
                                    &h0new[(size_t)(m0 + r) * 512 + c4]);
                else          v = *reinterpret_cast<const float4*>(
                                    &h1old[(size_t)(m0 + r) * 512 + (c4 - 512)]);
                *reinterpret_cast<float4*>(&as_[r * 1024 + c4]) = v;
            }
            __syncthreads();
            float s[2];
            coreN<1024, 2>(A.Wg1, as_, n0, lane, w, s);
            const int n = n0 + lane;
            const float bias = (n < 512) ? A.bu1[n] : A.br1[n - 512];
            #pragma unroll
            for (int i = 0; i < 2; ++i){
                const int m = m0 + w * 2 + i;
                float pre = s[i] + bias;
                A.ur1[(size_t)m * 1024 + n] = 1.f / (1.f + __expf(-pre));
            }
        }
        gridbar(A.flags, ++gen);

        // ---- P4: h1new = u*h + (1-u)*tanh([h0new|r*h1old] @ Wc1 + bc1) ----
        {
            const int m0 = (blk >> 3) * 4, n0 = (blk & 7) * 64;
            for (int q = 0; q < 4; ++q){
                int idx = tid + q * 256, r = idx >> 8, c4 = (idx & 255) << 2;
                float4 v;
                if (c4 < 512){
                    v = *reinterpret_cast<const float4*>(&h0new[(size_t)(m0 + r) * 512 + c4]);
                } else {
                    const float4 rv = *reinterpret_cast<const float4*>(
                        &A.ur1[(size_t)(m0 + r) * 1024 + 512 + (c4 - 512)]);
                    const float4 hv = *reinterpret_cast<const float4*>(
                        &h1old[(size_t)(m0 + r) * 512 + (c4 - 512)]);
                    v.x = rv.x*hv.x; v.y = rv.y*hv.y; v.z = rv.z*hv.z; v.w = rv.w*hv.w;
                }
                *reinterpret_cast<float4*>(&as_[r * 1024 + c4]) = v;
            }
            __syncthreads();
            float s[1];
            coreN<1024, 1>(A.Wc1, as_, n0, lane, w, s);
            const int n = n0 + lane;
            const int m = m0 + w;
            float cand = tanhf(s[0] + A.bc1[n]);
            float u = A.ur1[(size_t)m * 1024 + n];
            float h = h1old[(size_t)m * 512 + n];
            float h2 = u * h + (1.f - u) * cand;
            h1new[(size_t)m * 512 + n] = h2;
            A.xs16[((size_t)t * B_ + m) * 512 + n] = f2bf(h2);
            if (t == T_ - 1) A.fsout[65536 + (size_t)m * 512 + n] = h2;
        }
        gridbar(A.flags, ++gen);
    }
}

// ---------------------------------------------------------------------------
// Logits GEMM
// ---------------------------------------------------------------------------
__global__ void __launch_bounds__(256) k_logits(const unsigned short* __restrict__ xs16,
                                                const unsigned short* __restrict__ WbT,
                                                const float* __restrict__ b_out,
                                                float* __restrict__ out){
    __shared__ unsigned short al[128 * 72];
    __shared__ unsigned short bl[128 * 72];
    const int n0 = blockIdx.x * 128;
    const int t  = blockIdx.y;
    const int m0 = t * 128;
    const int tid = threadIdx.x;
    const int lane = tid & 63;
    const int wid = tid >> 6;
    const int wm = (wid >> 1) * 64;
    const int wn = (wid & 1) * 64;
    f32x4 acc[4][4];
    #pragma unroll
    for (int i = 0; i < 4; ++i)
        #pragma unroll
        for (int jj = 0; jj < 4; ++jj)
            acc[i][jj] = (f32x4){0.f, 0.f, 0.f, 0.f};

    for (int c = 0; c < 8; ++c){
        const int k0 = c * 64;
        __syncthreads();
        #pragma unroll
        for (int q = 0; q < 4; ++q){
            const int li = tid + q * 256;
            const int row = li >> 3;
            const int seg = li & 7;
            *reinterpret_cast<u16x8*>(&al[row * 72 + seg * 8]) =
                *reinterpret_cast<const u16x8*>(xs16 + (size_t)(m0 + row) * 512 + k0 + seg * 8);
            *reinterpret_cast<u16x8*>(&bl[row * 72 + seg * 8]) =
                *reinterpret_cast<const u16x8*>(WbT + (size_t)(n0 + row) * 512 + k0 + seg * 8);
        }
        __syncthreads();
        #pragma unroll
        for (int ks = 0; ks < 2; ++ks){
            bf16x8 af[4], bfr[4];
            #pragma unroll
            for (int f = 0; f < 4; ++f){
                af[f]  = *reinterpret_cast<const bf16x8*>(
                    &al[(wm + f * 16 + (lane & 15)) * 72 + ks * 32 + (lane >> 4) * 8]);
                bfr[f] = *reinterpret_cast<const bf16x8*>(
                    &bl[(wn + f * 16 + (lane & 15)) * 72 + ks * 32 + (lane >> 4) * 8]);
            }
            #pragma unroll
            for (int fm = 0; fm < 4; ++fm)
                #pragma unroll
                for (int fn = 0; fn < 4; ++fn)
                    acc[fm][fn] = __builtin_amdgcn_mfma_f32_16x16x32_bf16(
                        af[fm], bfr[fn], acc[fm][fn], 0, 0, 0);
        }
    }
    #pragma unroll
    for (int fm = 0; fm < 4; ++fm){
        #pragma unroll
        for (int fn = 0; fn < 4; ++fn){
            const int v = n0 + wn + fn * 16 + (lane & 15);
            if (v < V_){
                const float bo = b_out[v];
                #pragma unroll
                for (int mi = 0; mi < 4; ++mi){
                    const int b = wm + fm * 16 + (lane >> 4) * 4 + mi;
                    out[(size_t)b * (T_ * V_) + (size_t)t * V_ + v] = acc[fm][fn][mi] + bo;
                }
            }
        }
    }
}

// ---------------------------------------------------------------------------
extern "C" void kernel_launch(void* const* d_in, const int* in_sizes, int n_in,
                              void* d_out, int out_size, void* d_ws, size_t ws_size,
                              hipStream_t stream){
    const float* vgg  = (const float*)d_in[0];
    const int*   tok  = (const int*)  d_in[1];
    const float* emb  = (const float*)d_in[2];
    const float* Win  = (const float*)d_in[3];
    const float* bin  = (const float*)d_in[4];
    const float* Wu   = (const float*)d_in[5];
    const float* bu   = (const float*)d_in[6];
    const float* Wr   = (const float*)d_in[7];
    const float* br   = (const float*)d_in[8];
    const float* Wc   = (const float*)d_in[9];
    const float* bc   = (const float*)d_in[10];
    const float* Wout = (const float*)d_in[11];
    const float* bout = (const float*)d_in[12];
    float* out = (float*)d_out;

    // f32 workspace offsets (in floats)
    float* ws = (float*)d_ws;
    float* h0a  = ws;
    float* h0b  = ws + 65536;
    float* h1a  = ws + 131072;
    float* h1b  = ws + 196608;
    float* ur0  = ws + 262144;
    float* ur1  = ws + 393216;
    float* gx   = ws + 524288;     // [3840][1536] -> end 6422528
    float* h0p  = ws + 6422528;    // [8][128][512] (scratch, pre-recur only)
    unsigned* flags = (unsigned*)(ws + 6422528);  // aliases h0p AFTER k_h0r
    float* Wg0  = ws + 6946816;
    float* Wc0  = ws + 7471104;
    float* Wg1  = ws + 7733248;
    float* Wc1  = ws + 8781824;
    // u16 areas
    unsigned short* xs16   = (unsigned short*)((char*)d_ws + 37224960);
    unsigned short* WbT    = (unsigned short*)((char*)d_ws + 41157120);
    unsigned short* xemb16 = (unsigned short*)((char*)d_ws + 51511808);
    unsigned short* WxT    = (unsigned short*)((char*)d_ws + 55443968);

    const float* Wu0 = Wu, *Wu1 = Wu + 524288;
    const float* Wr0 = Wr, *Wr1 = Wr + 524288;
    const float* Wc0s = Wc, *Wc1s = Wc + 524288;

    // ---- setup (t-independent) ----
    k_castWT<<<dim3(158, 8), dim3(256), 0, stream>>>(Wout, WbT);
    k_castWxT<<<dim3(8, 8), dim3(256), 0, stream>>>(Wu0,  WxT);
    k_castWxT<<<dim3(8, 8), dim3(256), 0, stream>>>(Wr0,  WxT + 262144);
    k_castWxT<<<dim3(8, 8), dim3(256), 0, stream>>>(Wc0s, WxT + 524288);
    k_embed16<<<dim3(960), dim3(256), 0, stream>>>(tok, emb, xemb16);
    k_prepW<<<dim3(512),  dim3(256), 0, stream>>>(Wg0, Wu0,  Wr0,  512, 128);
    k_prepW<<<dim3(256),  dim3(256), 0, stream>>>(Wc0, Wc0s, Wc0s, 512, 128);
    k_prepW<<<dim3(1024), dim3(256), 0, stream>>>(Wg1, Wu1,  Wr1,  0,   256);
    k_prepW<<<dim3(512),  dim3(256), 0, stream>>>(Wc1, Wc1s, Wc1s, 0,   256);
    k_h0p<<<dim3(16, 8), dim3(256), 0, stream>>>(vgg, Win, h0p);
    k_h0r<<<dim3(64), dim3(256), 0, stream>>>(h0p, bin, h0a, h1a);
    k_zerobar<<<dim3(17), dim3(256), 0, stream>>>(flags);   // after k_h0r (aliases h0p)
    k_gx<<<dim3(12, 30), dim3(256), 0, stream>>>(xemb16, WxT, bu, br, bc, gx);

    // ---- persistent cooperative recurrence ----
    RecurArgs ra;
    ra.gx = gx; ra.Wg0 = Wg0; ra.Wc0 = Wc0; ra.Wg1 = Wg1; ra.Wc1 = Wc1;
    ra.bu1 = bu + 512; ra.br1 = br + 512; ra.bc1 = bc + 512;
    ra.h0a = h0a; ra.h0b = h0b; ra.h1a = h1a; ra.h1b = h1b;
    ra.ur0 = ur0; ra.ur1 = ur1;
    ra.xs16 = xs16; ra.fsout = out + 38400000; ra.flags = flags;
    void* args[] = { &ra };
    hipLaunchCooperativeKernel((const void*)k_recur, dim3(256), dim3(256), args, 0, stream);

    // ---- logits ----
    k_logits<<<dim3(79, 30), dim3(256), 0, stream>>>(xs16, WbT, bout, out);
}